// Round 13
// baseline (1132.116 us; speedup 1.0000x reference)
//
#include <hip/hip_runtime.h>
#include <hip/hip_bf16.h>

// ---------------------------------------------------------------------------
// WindowsMultiheadAttention: 4096 windows x (L=49, E=256), 8 heads x d=32.
// R13: 512-thread workgroups (8 waves) per window, out-proj split to K2.
//  Wave w: m/row-quarter mq = w&3 (rows mq*16..+15), head-parity h = w>>2.
//  afrag[1][8] = 32 regs -> peak live ~150 regs, no spill by construction.
//  LDS 52224 B (Q/K/VT overlay dead winb; P private/wave; stg overlays Q at
//  end) -> 3 WG/CU = 24 waves/CU = 6 waves/SIMD (3x R10's occupancy).
//  K2 = R4-validated dense out-proj GEMM (M=200704, 4 WG/CU, no LDS).
// ---------------------------------------------------------------------------

typedef float  f32x4  __attribute__((ext_vector_type(4)));
typedef short  s16x8  __attribute__((ext_vector_type(8)));
typedef short  s16x4  __attribute__((ext_vector_type(4)));

#define MFMA16(a, b, c) __builtin_amdgcn_mfma_f32_16x16x32_bf16((a), (b), (c), 0, 0, 0)

static __device__ __forceinline__ unsigned short f2bf(float f) {
    __hip_bfloat16 h = __float2bfloat16(f);
    unsigned short u;
    __builtin_memcpy(&u, &h, 2);
    return u;
}

// ---- K1 LDS layout (bytes) --------------------------------------------------
// winb [64][264] bf16 @ 0 (33792): gather + afrag source; dead after b2.
//   overlays: Qb [64][72] @ 0 | Kb @ 9216 | VTb @ 18432  (27648 <= 33792)
//   stg [64][66] f32 @ 0 (16896) at the very end (Q/K dead)
// Pw [8][16][72] bf16 @ 33792 + wave*2304 (18432)  -> total 52224 -> 3 WG/CU
#define K1_SMEM 52224
#define WS 264
#define QS 72

__global__ __launch_bounds__(512, 6)
void wmha_attn_kernel(const float* __restrict__ x,
                      const float* __restrict__ bqkv,
                      const unsigned short* __restrict__ wq,  // [768][256] bf16
                      unsigned short* __restrict__ og,        // [200704][256] bf16
                      float* __restrict__ aout)               // [4096][49][49]
{
    extern __shared__ char smem[];
    unsigned short* winb = (unsigned short*)smem;            // [64][264]
    unsigned short* Qb   = (unsigned short*)smem;            // [64][72] overlay
    unsigned short* Kb   = (unsigned short*)(smem + 9216);   // [64][72]
    unsigned short* VTb  = (unsigned short*)(smem + 18432);  // [64][72]
    float* stg = (float*)smem;                               // [64][66] (end)

    const int tid  = threadIdx.x;
    const int wave = tid >> 6;    // 0..7
    const int lane = tid & 63;
    const int lx   = lane & 15;
    const int lg   = lane >> 4;
    const int mq   = wave & 3;    // m/row quarter (rows mq*16 .. +15)
    const int h    = wave >> 2;   // head parity within pair

    unsigned short* Pw = (unsigned short*)(smem + 33792 + wave * 2304); // [16][72]

    const int m  = blockIdx.x;
    const int b  = m >> 6;
    const int w  = m & 63;
    const int hk = w >> 3;
    const int wk = w & 7;
    const float* xb = x + (size_t)b * 3136 * 256;

    // ---- gather window into LDS (scramble); compile-time unrolled ----------
    #pragma unroll
    for (int ii = 0; ii < 7; ++ii) {
        const int k = tid + ii * 512;
        if (k < 3136) {
            const int p  = k >> 6;            // patch pos 0..48
            const int l4 = (k & 63) * 4;      // channel base c'
            const int ky = p / 7, kx = p - ky * 7;
            const int rimg = (hk * 7 + ky) * 56 + wk * 7 + kx;
            const float4 v = *(const float4*)&xb[rimg * 256 + l4];
            #pragma unroll
            for (int e = 0; e < 4; ++e) {
                const int j = (l4 + e) * 49 + p;   // l*256+c == c'*49+p
                winb[(j >> 8) * WS + (j & 255)] =
                    f2bf(e == 0 ? v.x : e == 1 ? v.y : e == 2 ? v.z : v.w);
            }
        }
    }
    #pragma unroll
    for (int ii = 0; ii < 2; ++ii) {              // zero pad rows 49..63
        const int i = tid + ii * 512;             // 960 total
        if (i < 960) {
            const int row = 49 + (i >> 6);
            const int c4  = (i & 63) * 4;
            *(s16x4*)&winb[row * WS + c4] = (s16x4){0, 0, 0, 0};
        }
    }
    __syncthreads();   // b1

    // ---- cache OWN m-quarter A-fragments (32 regs; mq only in address) -----
    s16x8 afrag[8];
    #pragma unroll
    for (int ks = 0; ks < 8; ++ks)
        afrag[ks] = *(const s16x8*)&winb[(mq * 16 + lx) * WS + ks * 32 + lg * 8];
    __syncthreads();   // b2: winb dead -> Q/K/VT overlay

    const float scale = 0.17677669529663687f;     // 1/sqrt(32)
    float pacc[4][4] = {};                        // [r][nt] attn-mean accum

    #pragma unroll 1
    for (int hp = 0; hp < 4; ++hp) {
        // ---- QKV: 6 of 12 n-tiles (nt = (w>>2) + 2i), own m-quarter,
        //      processed in 3 groups of 2 concurrent chains ------------------
        #pragma unroll
        for (int g = 0; g < 3; ++g) {
            const int ntA = h + 4 * g;            // (w>>2) + 2*(2g)
            const int ntB = ntA + 2;              // (w>>2) + 2*(2g+1)
            const int pA = ntA >> 2, sA = ntA & 3;
            const int pB = ntB >> 2, sB = ntB & 3;
            const int n0A = pA * 256 + hp * 64 + sA * 16;
            const int n0B = pB * 256 + hp * 64 + sB * 16;
            const unsigned short* wpA = wq + (size_t)(n0A + lx) * 256 + lg * 8;
            const unsigned short* wpB = wq + (size_t)(n0B + lx) * 256 + lg * 8;
            f32x4 accA = {}, accB = {};
            #pragma unroll
            for (int ks = 0; ks < 8; ++ks) {
                const s16x8 bbA = *(const s16x8*)(wpA + ks * 32);
                const s16x8 bbB = *(const s16x8*)(wpB + ks * 32);
                accA = MFMA16(afrag[ks], bbA, accA);
                accB = MFMA16(afrag[ks], bbB, accB);
            }
            const float biasA = bqkv[n0A + lx];
            const float biasB = bqkv[n0B + lx];
            // store A then B (wave-uniform part/sub branches)
            #pragma unroll
            for (int ab = 0; ab < 2; ++ab) {
                const int part = ab ? pB : pA;
                const int sub  = ab ? sB : sA;
                const f32x4 acc = ab ? accB : accA;
                const float bias = ab ? biasB : biasA;
                if (part == 0) {
                    #pragma unroll
                    for (int r = 0; r < 4; ++r)
                        Qb[(mq * 16 + lg * 4 + r) * QS + sub * 16 + lx] =
                            f2bf((acc[r] + bias) * scale);   // pre-scaled Q
                } else if (part == 1) {
                    #pragma unroll
                    for (int r = 0; r < 4; ++r)
                        Kb[(mq * 16 + lg * 4 + r) * QS + sub * 16 + lx] =
                            f2bf(acc[r] + bias);
                } else {
                    s16x4 pk;                     // V^T, packed b64 over tokens
                    #pragma unroll
                    for (int r = 0; r < 4; ++r)
                        pk[r] = (short)f2bf(acc[r] + bias);
                    *(s16x4*)&VTb[(sub * 16 + lx) * QS + mq * 16 + lg * 4] = pk;
                }
            }
        }
        __syncthreads();   // b_hp1: Q/K/VT ready

        // ---- scores = (Q*s) K^T for (head h, rows mq*16..+15) --------------
        const s16x8 qa = *(const s16x8*)&Qb[(mq * 16 + lx) * QS + h * 32 + lg * 8];
        f32x4 sacc[4] = {};
        #pragma unroll
        for (int nt = 0; nt < 4; ++nt) {
            const s16x8 kb = *(const s16x8*)&Kb[(nt * 16 + lx) * QS + h * 32 + lg * 8];
            sacc[nt] = MFMA16(qa, kb, sacc[nt]);
        }

        // ---- softmax in registers (no max-subtract: |scores| small) --------
        float pv[4][4];
        #pragma unroll
        for (int r = 0; r < 4; ++r) {
            const bool ok3 = (lx == 0);           // col 48+lx valid iff lx==0
            float e0 = __expf(sacc[0][r]);
            float e1 = __expf(sacc[1][r]);
            float e2 = __expf(sacc[2][r]);
            float e3 = ok3 ? __expf(sacc[3][r]) : 0.f;
            float sum = e0 + e1 + e2 + e3;
            #pragma unroll
            for (int s = 1; s < 16; s <<= 1) sum += __shfl_xor(sum, s);
            const float inv = 1.0f / sum;
            pv[r][0] = e0 * inv;
            pv[r][1] = e1 * inv;
            pv[r][2] = e2 * inv;
            pv[r][3] = e3 * inv;
            #pragma unroll
            for (int nt = 0; nt < 4; ++nt)
                pacc[r][nt] += pv[r][nt] * 0.125f;
        }

        // ---- write P to PRIVATE buffer (same-wave ordering, no barrier) ----
        #pragma unroll
        for (int r = 0; r < 4; ++r) {
            const int qr = lg * 4 + r;            // local row 0..15
            #pragma unroll
            for (int nt = 0; nt < 4; ++nt)
                Pw[qr * QS + nt * 16 + lx] = f2bf(pv[r][nt]);
        }

        // ---- PV: o(own rows, head cols) = P V; store to global og ----------
        s16x8 pa[2], vb[2][2];
        #pragma unroll
        for (int ks = 0; ks < 2; ++ks)
            pa[ks] = *(const s16x8*)&Pw[lx * QS + ks * 32 + lg * 8];
        #pragma unroll
        for (int nt = 0; nt < 2; ++nt)
            #pragma unroll
            for (int ks = 0; ks < 2; ++ks)
                vb[nt][ks] = *(const s16x8*)&VTb[(h * 32 + nt * 16 + lx) * QS + ks * 32 + lg * 8];
        f32x4 oacc[2] = {};
        #pragma unroll
        for (int ks = 0; ks < 2; ++ks)
            #pragma unroll
            for (int nt = 0; nt < 2; ++nt)
                oacc[nt] = MFMA16(pa[ks], vb[nt][ks], oacc[nt]);
        #pragma unroll
        for (int nt = 0; nt < 2; ++nt)
            #pragma unroll
            for (int r = 0; r < 4; ++r) {
                const int q = mq * 16 + lg * 4 + r;
                if (q < 49)
                    og[((size_t)m * 49 + q) * 256 +
                       hp * 64 + h * 32 + nt * 16 + lx] = f2bf(oacc[nt][r]);
            }
        __syncthreads();   // b_hp2: Q/K/VT reads done before next hp's writes
    }

    // ---- attn-mean: h0 waves stage into dead Q/K region (stride 66) --------
    if (h == 0) {
        #pragma unroll
        for (int r = 0; r < 4; ++r) {
            const int row = mq * 16 + lg * 4 + r;
            #pragma unroll
            for (int nt = 0; nt < 4; ++nt)
                stg[row * 66 + nt * 16 + lx] = pacc[r][nt];
        }
    }
    __syncthreads();   // b_stg

    if (h == 1) {
        float* abase = aout + (size_t)m * 2401;
        #pragma unroll
        for (int r = 0; r < 4; ++r) {
            const int q = mq * 16 + lg * 4 + r;
            if (q < 49) {
                #pragma unroll
                for (int nt = 0; nt < 4; ++nt) {
                    const int col = nt * 16 + lx;
                    if (col < 49)
                        abase[q * 49 + col] = stg[q * 66 + col] + pacc[r][nt];
                }
            }
        }
    }
}

// ---- K2: y = o @ Wo^T + b   (M=200704, N=256, K=256; no LDS/barriers) ------
__global__ __launch_bounds__(256, 4)
void wmha_oproj_kernel(const unsigned short* __restrict__ og,   // [200704][256]
                       const unsigned short* __restrict__ wo,   // [256][256]
                       const float* __restrict__ bout,
                       float* __restrict__ y)                   // [200704][256]
{
    const int tid  = threadIdx.x;
    const int wave = tid >> 6;
    const int lane = tid & 63;
    const int lx   = lane & 15;
    const int lg   = lane >> 4;
    const size_t base = (size_t)blockIdx.x * 64;
    const int n0w = wave * 64;

    f32x4 acc[4][4] = {};   // [nt][mt]
    #pragma unroll
    for (int ks = 0; ks < 8; ++ks) {
        s16x8 a[4], bfr[4];
        #pragma unroll
        for (int mt = 0; mt < 4; ++mt)
            a[mt] = *(const s16x8*)&og[(base + mt * 16 + lx) * 256 + ks * 32 + lg * 8];
        #pragma unroll
        for (int nt = 0; nt < 4; ++nt)
            bfr[nt] = *(const s16x8*)&wo[(size_t)(n0w + nt * 16 + lx) * 256 + ks * 32 + lg * 8];
        #pragma unroll
        for (int nt = 0; nt < 4; ++nt)
            #pragma unroll
            for (int mt = 0; mt < 4; ++mt)
                acc[nt][mt] = MFMA16(a[mt], bfr[nt], acc[nt][mt]);
    }
    #pragma unroll
    for (int nt = 0; nt < 4; ++nt) {
        const float bias = bout[n0w + nt * 16 + lx];
        #pragma unroll
        for (int mt = 0; mt < 4; ++mt)
            #pragma unroll
            for (int r = 0; r < 4; ++r)
                y[(base + mt * 16 + lg * 4 + r) * 256 + n0w + nt * 16 + lx] =
                    acc[nt][mt][r] + bias;
    }
}

// ---- weight conversion fp32 -> bf16 ---------------------------------------
__global__ void wmha_cvt_kernel(const float* __restrict__ w_in,
                                const float* __restrict__ w_out,
                                unsigned short* __restrict__ dq,
                                unsigned short* __restrict__ dw)
{
    const int idx = blockIdx.x * 256 + threadIdx.x;
    if (idx < 196608)      dq[idx] = f2bf(w_in[idx]);
    else                   dw[idx - 196608] = f2bf(w_out[idx - 196608]);
}

extern "C" void kernel_launch(void* const* d_in, const int* in_sizes, int n_in,
                              void* d_out, int out_size, void* d_ws, size_t ws_size,
                              hipStream_t stream) {
    const float* x    = (const float*)d_in[0];
    const float* w_in = (const float*)d_in[1];
    const float* b_in = (const float*)d_in[2];
    const float* w_o  = (const float*)d_in[3];
    const float* b_o  = (const float*)d_in[4];

    unsigned short* wq_bf = (unsigned short*)d_ws;
    unsigned short* wo_bf = wq_bf + 196608;
    unsigned short* og    = wq_bf + 262144;      // [200704][256] bf16 = 102.8 MB

    float* y  = (float*)d_out;
    float* aw = y + (size_t)4096 * 49 * 256;     // attn-mean output

    wmha_cvt_kernel<<<1024, 256, 0, stream>>>(w_in, w_o, wq_bf, wo_bf);

    hipFuncSetAttribute((const void*)wmha_attn_kernel,
                        hipFuncAttributeMaxDynamicSharedMemorySize, K1_SMEM);
    wmha_attn_kernel<<<4096, 512, K1_SMEM, stream>>>(x, b_in, wq_bf, og, aw);

    wmha_oproj_kernel<<<3136, 256, 0, stream>>>(og, wo_bf, b_o, y);
}

// Round 14
// 911.465 us; speedup vs baseline: 1.2421x; 1.2421x over previous
//
#include <hip/hip_runtime.h>
#include <hip/hip_bf16.h>

// ---------------------------------------------------------------------------
// WindowsMultiheadAttention: 4096 windows x (L=49, E=256), 8 heads x d=32.
// R14 = R13 structure with the register cap fixed: __launch_bounds__(512,4)
//  (R13's (512,6) capped regs at 512/6=85 < ~110 live -> total spill, 1.3 GB
//   scratch traffic/dispatch. (512,4) -> 128-reg budget, fits by arithmetic.)
//  Wave w of 8: m/row-quarter mq = w&3, head-parity h = w>>2. afrag[8]=32 regs.
//  2 WG/CU = 16 waves/CU = 4 waves/SIMD (2x R10's occupancy), LDS 52 KB.
//  K2 = R4-validated dense out-proj GEMM (M=200704, no LDS/barriers).
// ---------------------------------------------------------------------------

typedef float  f32x4  __attribute__((ext_vector_type(4)));
typedef short  s16x8  __attribute__((ext_vector_type(8)));
typedef short  s16x4  __attribute__((ext_vector_type(4)));

#define MFMA16(a, b, c) __builtin_amdgcn_mfma_f32_16x16x32_bf16((a), (b), (c), 0, 0, 0)

static __device__ __forceinline__ unsigned short f2bf(float f) {
    __hip_bfloat16 h = __float2bfloat16(f);
    unsigned short u;
    __builtin_memcpy(&u, &h, 2);
    return u;
}

// ---- K1 LDS layout (bytes) --------------------------------------------------
// winb [64][264] bf16 @ 0 (33792): gather + afrag source; dead after b2.
//   overlays: Qb [64][72] @ 0 | Kb @ 9216 | VTb @ 18432  (27648 <= 33792)
//   stg [64][66] f32 @ 0 (16896) at the very end (Q/K dead)
// Pw [8][16][72] bf16 @ 33792 + wave*2304 (18432)  -> total 52224
#define K1_SMEM 52224
#define WS 264
#define QS 72

__global__ __launch_bounds__(512, 4)
void wmha_attn_kernel(const float* __restrict__ x,
                      const float* __restrict__ bqkv,
                      const unsigned short* __restrict__ wq,  // [768][256] bf16
                      unsigned short* __restrict__ og,        // [200704][256] bf16
                      float* __restrict__ aout)               // [4096][49][49]
{
    extern __shared__ char smem[];
    unsigned short* winb = (unsigned short*)smem;            // [64][264]
    unsigned short* Qb   = (unsigned short*)smem;            // [64][72] overlay
    unsigned short* Kb   = (unsigned short*)(smem + 9216);   // [64][72]
    unsigned short* VTb  = (unsigned short*)(smem + 18432);  // [64][72]
    float* stg = (float*)smem;                               // [64][66] (end)

    const int tid  = threadIdx.x;
    const int wave = tid >> 6;    // 0..7
    const int lane = tid & 63;
    const int lx   = lane & 15;
    const int lg   = lane >> 4;
    const int mq   = wave & 3;    // m/row quarter (rows mq*16 .. +15)
    const int h    = wave >> 2;   // head parity within pair

    unsigned short* Pw = (unsigned short*)(smem + 33792 + wave * 2304); // [16][72]

    const int m  = blockIdx.x;
    const int b  = m >> 6;
    const int w  = m & 63;
    const int hk = w >> 3;
    const int wk = w & 7;
    const float* xb = x + (size_t)b * 3136 * 256;

    // ---- gather window into LDS (scramble); compile-time unrolled ----------
    #pragma unroll
    for (int ii = 0; ii < 7; ++ii) {
        const int k = tid + ii * 512;
        if (k < 3136) {
            const int p  = k >> 6;            // patch pos 0..48
            const int l4 = (k & 63) * 4;      // channel base c'
            const int ky = p / 7, kx = p - ky * 7;
            const int rimg = (hk * 7 + ky) * 56 + wk * 7 + kx;
            const float4 v = *(const float4*)&xb[rimg * 256 + l4];
            #pragma unroll
            for (int e = 0; e < 4; ++e) {
                const int j = (l4 + e) * 49 + p;   // l*256+c == c'*49+p
                winb[(j >> 8) * WS + (j & 255)] =
                    f2bf(e == 0 ? v.x : e == 1 ? v.y : e == 2 ? v.z : v.w);
            }
        }
    }
    #pragma unroll
    for (int ii = 0; ii < 2; ++ii) {              // zero pad rows 49..63
        const int i = tid + ii * 512;             // 960 total
        if (i < 960) {
            const int row = 49 + (i >> 6);
            const int c4  = (i & 63) * 4;
            *(s16x4*)&winb[row * WS + c4] = (s16x4){0, 0, 0, 0};
        }
    }
    __syncthreads();   // b1

    // ---- cache OWN m-quarter A-fragments (32 regs; mq only in address) -----
    s16x8 afrag[8];
    #pragma unroll
    for (int ks = 0; ks < 8; ++ks)
        afrag[ks] = *(const s16x8*)&winb[(mq * 16 + lx) * WS + ks * 32 + lg * 8];
    __syncthreads();   // b2: winb dead -> Q/K/VT overlay

    const float scale = 0.17677669529663687f;     // 1/sqrt(32)
    float pacc[4][4] = {};                        // [r][nt] attn-mean accum

    #pragma unroll 1
    for (int hp = 0; hp < 4; ++hp) {
        // ---- QKV: 6 of 12 n-tiles (nt = h + 2i), own m-quarter,
        //      3 groups of 2 concurrent chains --------------------------------
        #pragma unroll
        for (int g = 0; g < 3; ++g) {
            const int ntA = h + 4 * g;
            const int ntB = ntA + 2;
            const int pA = ntA >> 2, sA = ntA & 3;
            const int pB = ntB >> 2, sB = ntB & 3;
            const int n0A = pA * 256 + hp * 64 + sA * 16;
            const int n0B = pB * 256 + hp * 64 + sB * 16;
            const unsigned short* wpA = wq + (size_t)(n0A + lx) * 256 + lg * 8;
            const unsigned short* wpB = wq + (size_t)(n0B + lx) * 256 + lg * 8;
            f32x4 accA = {}, accB = {};
            #pragma unroll
            for (int ks = 0; ks < 8; ++ks) {
                const s16x8 bbA = *(const s16x8*)(wpA + ks * 32);
                const s16x8 bbB = *(const s16x8*)(wpB + ks * 32);
                accA = MFMA16(afrag[ks], bbA, accA);
                accB = MFMA16(afrag[ks], bbB, accB);
            }
            const float biasA = bqkv[n0A + lx];
            const float biasB = bqkv[n0B + lx];
            #pragma unroll
            for (int ab = 0; ab < 2; ++ab) {      // wave-uniform branches
                const int part = ab ? pB : pA;
                const int sub  = ab ? sB : sA;
                const f32x4 acc = ab ? accB : accA;
                const float bias = ab ? biasB : biasA;
                if (part == 0) {
                    #pragma unroll
                    for (int r = 0; r < 4; ++r)
                        Qb[(mq * 16 + lg * 4 + r) * QS + sub * 16 + lx] =
                            f2bf((acc[r] + bias) * scale);   // pre-scaled Q
                } else if (part == 1) {
                    #pragma unroll
                    for (int r = 0; r < 4; ++r)
                        Kb[(mq * 16 + lg * 4 + r) * QS + sub * 16 + lx] =
                            f2bf(acc[r] + bias);
                } else {
                    s16x4 pk;                     // V^T, packed b64 over tokens
                    #pragma unroll
                    for (int r = 0; r < 4; ++r)
                        pk[r] = (short)f2bf(acc[r] + bias);
                    *(s16x4*)&VTb[(sub * 16 + lx) * QS + mq * 16 + lg * 4] = pk;
                }
            }
        }
        __syncthreads();   // b_hp1: Q/K/VT ready

        // ---- scores = (Q*s) K^T for (head h, rows mq*16..+15) --------------
        const s16x8 qa = *(const s16x8*)&Qb[(mq * 16 + lx) * QS + h * 32 + lg * 8];
        f32x4 sacc[4] = {};
        #pragma unroll
        for (int nt = 0; nt < 4; ++nt) {
            const s16x8 kb = *(const s16x8*)&Kb[(nt * 16 + lx) * QS + h * 32 + lg * 8];
            sacc[nt] = MFMA16(qa, kb, sacc[nt]);
        }

        // ---- softmax in registers (no max-subtract: |scores| small) --------
        float pv[4][4];
        #pragma unroll
        for (int r = 0; r < 4; ++r) {
            const bool ok3 = (lx == 0);           // col 48+lx valid iff lx==0
            float e0 = __expf(sacc[0][r]);
            float e1 = __expf(sacc[1][r]);
            float e2 = __expf(sacc[2][r]);
            float e3 = ok3 ? __expf(sacc[3][r]) : 0.f;
            float sum = e0 + e1 + e2 + e3;
            #pragma unroll
            for (int s = 1; s < 16; s <<= 1) sum += __shfl_xor(sum, s);
            const float inv = 1.0f / sum;
            pv[r][0] = e0 * inv;
            pv[r][1] = e1 * inv;
            pv[r][2] = e2 * inv;
            pv[r][3] = e3 * inv;
            #pragma unroll
            for (int nt = 0; nt < 4; ++nt)
                pacc[r][nt] += pv[r][nt] * 0.125f;
        }

        // ---- write P to PRIVATE buffer (same-wave ordering, no barrier) ----
        #pragma unroll
        for (int r = 0; r < 4; ++r) {
            const int qr = lg * 4 + r;            // local row 0..15
            #pragma unroll
            for (int nt = 0; nt < 4; ++nt)
                Pw[qr * QS + nt * 16 + lx] = f2bf(pv[r][nt]);
        }

        // ---- PV: o(own rows, head cols) = P V; store to global og ----------
        s16x8 pa[2], vb[2][2];
        #pragma unroll
        for (int ks = 0; ks < 2; ++ks)
            pa[ks] = *(const s16x8*)&Pw[lx * QS + ks * 32 + lg * 8];
        #pragma unroll
        for (int nt = 0; nt < 2; ++nt)
            #pragma unroll
            for (int ks = 0; ks < 2; ++ks)
                vb[nt][ks] = *(const s16x8*)&VTb[(h * 32 + nt * 16 + lx) * QS + ks * 32 + lg * 8];
        f32x4 oacc[2] = {};
        #pragma unroll
        for (int ks = 0; ks < 2; ++ks)
            #pragma unroll
            for (int nt = 0; nt < 2; ++nt)
                oacc[nt] = MFMA16(pa[ks], vb[nt][ks], oacc[nt]);
        #pragma unroll
        for (int nt = 0; nt < 2; ++nt)
            #pragma unroll
            for (int r = 0; r < 4; ++r) {
                const int q = mq * 16 + lg * 4 + r;
                if (q < 49)
                    og[((size_t)m * 49 + q) * 256 +
                       hp * 64 + h * 32 + nt * 16 + lx] = f2bf(oacc[nt][r]);
            }
        __syncthreads();   // b_hp2: Q/K/VT reads done before next hp's writes
    }

    // ---- attn-mean: h0 waves stage into dead Q/K region (stride 66) --------
    if (h == 0) {
        #pragma unroll
        for (int r = 0; r < 4; ++r) {
            const int row = mq * 16 + lg * 4 + r;
            #pragma unroll
            for (int nt = 0; nt < 4; ++nt)
                stg[row * 66 + nt * 16 + lx] = pacc[r][nt];
        }
    }
    __syncthreads();   // b_stg

    if (h == 1) {
        float* abase = aout + (size_t)m * 2401;
        #pragma unroll
        for (int r = 0; r < 4; ++r) {
            const int q = mq * 16 + lg * 4 + r;
            if (q < 49) {
                #pragma unroll
                for (int nt = 0; nt < 4; ++nt) {
                    const int col = nt * 16 + lx;
                    if (col < 49)
                        abase[q * 49 + col] = stg[q * 66 + col] + pacc[r][nt];
                }
            }
        }
    }
}

// ---- K2: y = o @ Wo^T + b   (M=200704, N=256, K=256; no LDS/barriers) ------
__global__ __launch_bounds__(256, 4)
void wmha_oproj_kernel(const unsigned short* __restrict__ og,   // [200704][256]
                       const unsigned short* __restrict__ wo,   // [256][256]
                       const float* __restrict__ bout,
                       float* __restrict__ y)                   // [200704][256]
{
    const int tid  = threadIdx.x;
    const int wave = tid >> 6;
    const int lane = tid & 63;
    const int lx   = lane & 15;
    const int lg   = lane >> 4;
    const size_t base = (size_t)blockIdx.x * 64;
    const int n0w = wave * 64;

    f32x4 acc[4][4] = {};   // [nt][mt]
    #pragma unroll
    for (int ks = 0; ks < 8; ++ks) {
        s16x8 a[4], bfr[4];
        #pragma unroll
        for (int mt = 0; mt < 4; ++mt)
            a[mt] = *(const s16x8*)&og[(base + mt * 16 + lx) * 256 + ks * 32 + lg * 8];
        #pragma unroll
        for (int nt = 0; nt < 4; ++nt)
            bfr[nt] = *(const s16x8*)&wo[(size_t)(n0w + nt * 16 + lx) * 256 + ks * 32 + lg * 8];
        #pragma unroll
        for (int nt = 0; nt < 4; ++nt)
            #pragma unroll
            for (int mt = 0; mt < 4; ++mt)
                acc[nt][mt] = MFMA16(a[mt], bfr[nt], acc[nt][mt]);
    }
    #pragma unroll
    for (int nt = 0; nt < 4; ++nt) {
        const float bias = bout[n0w + nt * 16 + lx];
        #pragma unroll
        for (int mt = 0; mt < 4; ++mt)
            #pragma unroll
            for (int r = 0; r < 4; ++r)
                y[(base + mt * 16 + lg * 4 + r) * 256 + n0w + nt * 16 + lx] =
                    acc[nt][mt][r] + bias;
    }
}

// ---- weight conversion fp32 -> bf16 ---------------------------------------
__global__ void wmha_cvt_kernel(const float* __restrict__ w_in,
                                const float* __restrict__ w_out,
                                unsigned short* __restrict__ dq,
                                unsigned short* __restrict__ dw)
{
    const int idx = blockIdx.x * 256 + threadIdx.x;
    if (idx < 196608)      dq[idx] = f2bf(w_in[idx]);
    else                   dw[idx - 196608] = f2bf(w_out[idx - 196608]);
}

extern "C" void kernel_launch(void* const* d_in, const int* in_sizes, int n_in,
                              void* d_out, int out_size, void* d_ws, size_t ws_size,
                              hipStream_t stream) {
    const float* x    = (const float*)d_in[0];
    const float* w_in = (const float*)d_in[1];
    const float* b_in = (const float*)d_in[2];
    const float* w_o  = (const float*)d_in[3];
    const float* b_o  = (const float*)d_in[4];

    unsigned short* wq_bf = (unsigned short*)d_ws;
    unsigned short* wo_bf = wq_bf + 196608;
    unsigned short* og    = wq_bf + 262144;      // [200704][256] bf16 = 102.8 MB

    float* y  = (float*)d_out;
    float* aw = y + (size_t)4096 * 49 * 256;     // attn-mean output

    wmha_cvt_kernel<<<1024, 256, 0, stream>>>(w_in, w_o, wq_bf, wo_bf);

    hipFuncSetAttribute((const void*)wmha_attn_kernel,
                        hipFuncAttributeMaxDynamicSharedMemorySize, K1_SMEM);
    wmha_attn_kernel<<<4096, 512, K1_SMEM, stream>>>(x, b_in, wq_bf, og, aw);

    wmha_oproj_kernel<<<3136, 256, 0, stream>>>(og, wo_bf, b_o, y);
}

// Round 15
// 364.339 us; speedup vs baseline: 3.1073x; 2.5017x over previous
//
#include <hip/hip_runtime.h>
#include <hip/hip_bf16.h>

// ---------------------------------------------------------------------------
// WindowsMultiheadAttention: 4096 windows x (L=49, E=256), 8 heads x d=32.
// R15 = R10 (best: 391 us) + serial-chain cuts at fixed occupancy:
//  - shuffle-free softmax: unnormalized E -> private P; row-sums via a
//    ones-MFMA (C-layout rows align with pv rows); normalize at PV store.
//    Deletes 32 __shfl_xor + 4-deep chains per hp.
//  - out-projection: 2 concurrent nt-chains (reg-audited: ~224 <= 256).
// Occupancy route closed by R4/R6/R8/R11/R13/R14 measurements.
// ---------------------------------------------------------------------------

typedef float  f32x4  __attribute__((ext_vector_type(4)));
typedef short  s16x8  __attribute__((ext_vector_type(8)));
typedef short  s16x4  __attribute__((ext_vector_type(4)));

#define MFMA16(a, b, c) __builtin_amdgcn_mfma_f32_16x16x32_bf16((a), (b), (c), 0, 0, 0)

static __device__ __forceinline__ unsigned short f2bf(float f) {
    __hip_bfloat16 h = __float2bfloat16(f);
    unsigned short u;
    __builtin_memcpy(&u, &h, 2);
    return u;
}

// ---- LDS layout (bytes) ----------------------------------------------------
// winb/ob [64][264] bf16 @ 0      (33792)
// Qb      [64][72]  bf16 @ 33792  (9216)
// Kb      [64][72]  bf16 @ 43008  (9216)
// VTb     [64][72]  bf16 @ 52224  (9216)
// Pw      [4][32][72] bf16 @ 61440 (18432)   per-wave private (unnormalized E)
// stg     [64][66]  f32  @ 33792  (16896)    overlays dead Q/K at END
#define SMEM_BYTES 79872
#define WS 264
#define QS 72

__global__ __launch_bounds__(256, 2)
void wmha_fused_kernel(const float* __restrict__ x,
                       const float* __restrict__ bqkv,
                       const float* __restrict__ bout,
                       const unsigned short* __restrict__ wq,   // [768][256] bf16
                       const unsigned short* __restrict__ wo,   // [256][256] bf16
                       float* __restrict__ yout,                // [4096][49][256]
                       float* __restrict__ aout)                // [4096][49][49]
{
    extern __shared__ char smem[];
    unsigned short* winb = (unsigned short*)smem;             // [64][264], later ob
    unsigned short* Qb   = (unsigned short*)(smem + 33792);   // [64][72]
    unsigned short* Kb   = (unsigned short*)(smem + 43008);   // [64][72]
    unsigned short* VTb  = (unsigned short*)(smem + 52224);   // [64][72]
    float* stg = (float*)(smem + 33792);                      // [64][66] f32 (end)

    const int tid  = threadIdx.x;
    const int wave = tid >> 6;
    const int lane = tid & 63;
    const int lx   = lane & 15;
    const int lg   = lane >> 4;
    const int h    = wave & 1;    // head within pair
    const int mh   = wave >> 1;   // M half

    unsigned short* Pw = (unsigned short*)(smem + 61440 + wave * 4608); // [32][72]

    const int m  = blockIdx.x;
    const int b  = m >> 6;
    const int w  = m & 63;
    const int hk = w >> 3;
    const int wk = w & 7;
    const float* xb = x + (size_t)b * 3136 * 256;

    // ---- gather window into LDS (scramble); compile-time unrolled ----------
    #pragma unroll
    for (int ii = 0; ii < 13; ++ii) {
        const int k = tid + ii * 256;
        if (k < 3136) {
            const int p  = k >> 6;
            const int l4 = (k & 63) * 4;
            const int ky = p / 7, kx = p - ky * 7;
            const int rimg = (hk * 7 + ky) * 56 + wk * 7 + kx;
            const float4 v = *(const float4*)&xb[rimg * 256 + l4];
            #pragma unroll
            for (int e = 0; e < 4; ++e) {
                const int j = (l4 + e) * 49 + p;   // l*256+c == c'*49+p
                winb[(j >> 8) * WS + (j & 255)] =
                    f2bf(e == 0 ? v.x : e == 1 ? v.y : e == 2 ? v.z : v.w);
            }
        }
    }
    // zero pad rows 49..63 (vectorized b64)
    #pragma unroll
    for (int ii = 0; ii < 4; ++ii) {
        const int i = tid + ii * 256;         // 960 total
        if (i < 960) {
            const int row = 49 + (i >> 6);
            const int c4  = (i & 63) * 4;
            *(s16x4*)&winb[row * WS + c4] = (s16x4){0, 0, 0, 0};
        }
    }
    __syncthreads();   // b1

    // ---- cache win A-fragments in registers (128 regs) ---------------------
    s16x8 afrag[4][8];
    #pragma unroll
    for (int mt = 0; mt < 4; ++mt)
        #pragma unroll
        for (int ks = 0; ks < 8; ++ks)
            afrag[mt][ks] = *(const s16x8*)&winb[(lx + mt * 16) * WS + ks * 32 + lg * 8];
    __syncthreads();   // b2: winb dead -> region becomes ob

    unsigned short* ob = winb;
    const float scale = 0.17677669529663687f;     // 1/sqrt(32)
    float pacc[2][4][4] = {};                     // [mt][r][nt] attn-mean accum

    // bf16 ones B-fragment for row-sum MFMA (1.0 = 0x3F80)
    s16x8 onesf;
    #pragma unroll
    for (int j = 0; j < 8; ++j) onesf[j] = (short)0x3F80;

    #pragma unroll 1
    for (int hp = 0; hp < 4; ++hp) {
        // ---- QKV projection: this wave's 3 n-tiles (of 12), tile-serial ----
        #pragma unroll
        for (int i = 0; i < 3; ++i) {
            const int t = wave * 3 + i;
            const int part = t >> 2;              // 0=Q 1=K 2=V
            const int sub  = t & 3;               // 16-col chunk of 64-col pair
            const int n0 = part * 256 + hp * 64 + sub * 16;
            f32x4 acc[4] = {};
            const unsigned short* wp = wq + (size_t)(n0 + lx) * 256 + lg * 8;
            #pragma unroll
            for (int ks = 0; ks < 8; ++ks) {
                const s16x8 bb = *(const s16x8*)(wp + ks * 32);
                #pragma unroll
                for (int mt = 0; mt < 4; ++mt)
                    acc[mt] = MFMA16(afrag[mt][ks], bb, acc[mt]);
            }
            const float bias = bqkv[n0 + lx];
            if (part == 0) {
                #pragma unroll
                for (int mt = 0; mt < 4; ++mt)
                    #pragma unroll
                    for (int r = 0; r < 4; ++r)
                        Qb[(mt * 16 + lg * 4 + r) * QS + sub * 16 + lx] =
                            f2bf((acc[mt][r] + bias) * scale);   // pre-scaled Q
            } else if (part == 1) {
                #pragma unroll
                for (int mt = 0; mt < 4; ++mt)
                    #pragma unroll
                    for (int r = 0; r < 4; ++r)
                        Kb[(mt * 16 + lg * 4 + r) * QS + sub * 16 + lx] =
                            f2bf(acc[mt][r] + bias);
            } else {
                #pragma unroll
                for (int mt = 0; mt < 4; ++mt) {  // V^T, packed b64 over tokens
                    s16x4 pk;
                    #pragma unroll
                    for (int r = 0; r < 4; ++r)
                        pk[r] = (short)f2bf(acc[mt][r] + bias);
                    *(s16x4*)&VTb[(sub * 16 + lx) * QS + mt * 16 + lg * 4] = pk;
                }
            }
        }
        __syncthreads();   // b_hp1: Q/K/VT ready

        // ---- scores = (Q*s) K^T for (head h, rows mh*32..+31) --------------
        s16x8 qa[2];
        #pragma unroll
        for (int mt = 0; mt < 2; ++mt)
            qa[mt] = *(const s16x8*)&Qb[(mh * 32 + mt * 16 + lx) * QS + h * 32 + lg * 8];
        f32x4 sacc[2][4] = {};
        #pragma unroll
        for (int nt = 0; nt < 4; ++nt) {
            const s16x8 kb = *(const s16x8*)&Kb[(nt * 16 + lx) * QS + h * 32 + lg * 8];
            #pragma unroll
            for (int mt = 0; mt < 2; ++mt)
                sacc[mt][nt] = MFMA16(qa[mt], kb, sacc[mt][nt]);
        }

        // ---- exp only (no shuffles); E stays UNNORMALIZED ------------------
        float pv[2][4][4];
        #pragma unroll
        for (int mt = 0; mt < 2; ++mt) {
            #pragma unroll
            for (int r = 0; r < 4; ++r) {
                const bool ok3 = (lx == 0);       // col 48+lx valid iff lx==0
                pv[mt][r][0] = __expf(sacc[mt][0][r]);
                pv[mt][r][1] = __expf(sacc[mt][1][r]);
                pv[mt][r][2] = __expf(sacc[mt][2][r]);
                pv[mt][r][3] = ok3 ? __expf(sacc[mt][3][r]) : 0.f;
            }
        }

        // ---- write unnormalized E to PRIVATE buffer (no barrier) -----------
        #pragma unroll
        for (int mt = 0; mt < 2; ++mt)
            #pragma unroll
            for (int r = 0; r < 4; ++r) {
                const int qr = mt * 16 + lg * 4 + r;   // local row 0..31
                #pragma unroll
                for (int nt = 0; nt < 4; ++nt)
                    Pw[qr * QS + nt * 16 + lx] = f2bf(pv[mt][r][nt]);
            }

        // ---- read E fragments; row-sums via ones-MFMA ----------------------
        s16x8 pa[2][2];
        #pragma unroll
        for (int mt = 0; mt < 2; ++mt)
            #pragma unroll
            for (int ks = 0; ks < 2; ++ks)
                pa[mt][ks] = *(const s16x8*)&Pw[(mt * 16 + lx) * QS + ks * 32 + lg * 8];
        f32x4 ssum[2] = {};
        #pragma unroll
        for (int ks = 0; ks < 2; ++ks)
            #pragma unroll
            for (int mt = 0; mt < 2; ++mt)
                ssum[mt] = MFMA16(pa[mt][ks], onesf, ssum[mt]);
        // inv per row; D rows of ssum align with pv rows (lg*4+r)
        float invv[2][4];
        #pragma unroll
        for (int mt = 0; mt < 2; ++mt)
            #pragma unroll
            for (int r = 0; r < 4; ++r) {
                invv[mt][r] = 1.0f / ssum[mt][r];
                const float w8 = invv[mt][r] * 0.125f;
                #pragma unroll
                for (int nt = 0; nt < 4; ++nt)
                    pacc[mt][r][nt] += pv[mt][r][nt] * w8;
            }

        // ---- PV: o = (E V) * inv -------------------------------------------
        s16x8 vb[2][2];
        #pragma unroll
        for (int nt = 0; nt < 2; ++nt)
            #pragma unroll
            for (int ks = 0; ks < 2; ++ks)
                vb[nt][ks] = *(const s16x8*)&VTb[(h * 32 + nt * 16 + lx) * QS + ks * 32 + lg * 8];
        f32x4 oacc[2][2] = {};
        #pragma unroll
        for (int ks = 0; ks < 2; ++ks)
            #pragma unroll
            for (int mt = 0; mt < 2; ++mt)
                #pragma unroll
                for (int nt = 0; nt < 2; ++nt)
                    oacc[mt][nt] = MFMA16(pa[mt][ks], vb[nt][ks], oacc[mt][nt]);
        #pragma unroll
        for (int mt = 0; mt < 2; ++mt)
            #pragma unroll
            for (int nt = 0; nt < 2; ++nt)
                #pragma unroll
                for (int r = 0; r < 4; ++r)
                    ob[(mh * 32 + mt * 16 + lg * 4 + r) * WS +
                       hp * 64 + h * 32 + nt * 16 + lx] =
                        f2bf(oacc[mt][nt][r] * invv[mt][r]);
        __syncthreads();   // b_hp2: Q/K/VT reads done before next hp's QKV
    }

    // ---- attn-mean: h0 waves stage into dead Q/K region --------------------
    if (h == 0) {
        #pragma unroll
        for (int mt = 0; mt < 2; ++mt)
            #pragma unroll
            for (int r = 0; r < 4; ++r) {
                const int row = mh * 32 + mt * 16 + lg * 4 + r;
                #pragma unroll
                for (int nt = 0; nt < 4; ++nt)
                    stg[row * 66 + nt * 16 + lx] = pacc[mt][r][nt];
            }
    }
    // reload afrag from o (winb region)
    #pragma unroll
    for (int mt = 0; mt < 4; ++mt)
        #pragma unroll
        for (int ks = 0; ks < 8; ++ks)
            afrag[mt][ks] = *(const s16x8*)&ob[(lx + mt * 16) * WS + ks * 32 + lg * 8];
    __syncthreads();   // b_stg

    // ---- h1 waves combine + store attention-mean ---------------------------
    if (h == 1) {
        float* abase = aout + (size_t)m * 2401;
        #pragma unroll
        for (int mt = 0; mt < 2; ++mt)
            #pragma unroll
            for (int r = 0; r < 4; ++r) {
                const int q = mh * 32 + mt * 16 + lg * 4 + r;
                if (q < 49) {
                    #pragma unroll
                    for (int nt = 0; nt < 4; ++nt) {
                        const int col = nt * 16 + lx;
                        if (col < 49)
                            abase[q * 49 + col] = stg[q * 66 + col] + pacc[mt][r][nt];
                    }
                }
            }
    }

    // ---- out projection: 2 concurrent nt-chains (pacc/pv dead here) --------
    float* ybase = yout + (size_t)m * 12544;
    #pragma unroll
    for (int np = 0; np < 2; ++np) {
        const int n0A = wave * 64 + np * 32;
        const int n0B = n0A + 16;
        const unsigned short* wpA = wo + (size_t)(n0A + lx) * 256 + lg * 8;
        const unsigned short* wpB = wo + (size_t)(n0B + lx) * 256 + lg * 8;
        f32x4 accA[4] = {}, accB[4] = {};
        #pragma unroll
        for (int ks = 0; ks < 8; ++ks) {
            const s16x8 bA = *(const s16x8*)(wpA + ks * 32);
            const s16x8 bB = *(const s16x8*)(wpB + ks * 32);
            #pragma unroll
            for (int mt = 0; mt < 4; ++mt) {
                accA[mt] = MFMA16(afrag[mt][ks], bA, accA[mt]);
                accB[mt] = MFMA16(afrag[mt][ks], bB, accB[mt]);
            }
        }
        const float biasA = bout[n0A + lx];
        const float biasB = bout[n0B + lx];
        #pragma unroll
        for (int mt = 0; mt < 4; ++mt) {
            #pragma unroll
            for (int r = 0; r < 4; ++r) {
                const int q = mt * 16 + lg * 4 + r;
                if (q < 49) {
                    ybase[q * 256 + n0A + lx] = accA[mt][r] + biasA;
                    ybase[q * 256 + n0B + lx] = accB[mt][r] + biasB;
                }
            }
        }
    }
}

// ---- weight conversion fp32 -> bf16 ---------------------------------------
__global__ void wmha_cvt_kernel(const float* __restrict__ w_in,
                                const float* __restrict__ w_out,
                                unsigned short* __restrict__ dq,
                                unsigned short* __restrict__ dw)
{
    const int idx = blockIdx.x * 256 + threadIdx.x;
    if (idx < 196608)      dq[idx] = f2bf(w_in[idx]);
    else                   dw[idx - 196608] = f2bf(w_out[idx - 196608]);
}

extern "C" void kernel_launch(void* const* d_in, const int* in_sizes, int n_in,
                              void* d_out, int out_size, void* d_ws, size_t ws_size,
                              hipStream_t stream) {
    const float* x    = (const float*)d_in[0];
    const float* w_in = (const float*)d_in[1];
    const float* b_in = (const float*)d_in[2];
    const float* w_o  = (const float*)d_in[3];
    const float* b_o  = (const float*)d_in[4];

    unsigned short* wq_bf = (unsigned short*)d_ws;
    unsigned short* wo_bf = wq_bf + 196608;

    float* y  = (float*)d_out;
    float* aw = y + (size_t)4096 * 49 * 256;   // 51380224

    wmha_cvt_kernel<<<1024, 256, 0, stream>>>(w_in, w_o, wq_bf, wo_bf);

    hipFuncSetAttribute((const void*)wmha_fused_kernel,
                        hipFuncAttributeMaxDynamicSharedMemorySize, SMEM_BYTES);
    wmha_fused_kernel<<<4096, 256, SMEM_BYTES, stream>>>(
        x, b_in, b_o, wq_bf, wo_bf, y, aw);
}